// Round 18
// baseline (152.299 us; speedup 1.0000x reference)
//
#include <hip/hip_runtime.h>

#define TTOK 4096
#define DDIM 1024
#define FDIM 512
#define NEXP 8
#define HDIM 256
#define RLORA 64
#define CROWS 14336   // 4096 shared + up to 10240 padded expert rows

using u16 = unsigned short;
using f4v = __attribute__((ext_vector_type(4))) float;
using bfrag = __attribute__((ext_vector_type(8))) short;
using u16x8 = __attribute__((ext_vector_type(8))) unsigned short;

static __device__ __forceinline__ float bf2f(u16 u) {
  union { unsigned int u; float f; } x; x.u = ((unsigned int)u) << 16; return x.f;
}
static __device__ __forceinline__ u16 f2bf(float f) {
  union { float f; unsigned int u; } x; x.f = f;
  unsigned int r = (x.u + 0x7fffu + ((x.u >> 16) & 1u)) >> 16;
  return (u16)r;
}
static __device__ __forceinline__ float fq1(float t, float s) {
  float q = rintf(t / s);
  q = fminf(fmaxf(q, -128.f), 127.f);
  return q * s;
}

// ============ 256x256 BK=64 8-wave GEMM, counted-vmcnt phase schedule ============
// Stage batches per K-tile (2 loads each, strict order): b1=B-lo, b2=B-hi,
// b3=A-sub0 (rows 0-63 of both A regions), b4=A-sub1 (rows 64-127).
// Phase A: vmcnt(2) [b1-b3 of current tile retired; b4 in flight] -> barrier ->
//   stage next-tile b1,b2 -> read afr(mi0-3)+bfr -> 32 MFMA.
// Phase B: vmcnt(4) [b4 retired; next b1,b2 in flight] -> barrier ->
//   stage next b3,b4 -> read afr(mi4-7), reuse bfr regs -> 32 MFMA.
// Uniform issue order + barrier extends per-wave vmcnt to block-wide guarantee.
// Loads never drain to 0 in steady state (T4). Last tile: vmcnt(0) at phase B.
struct GemmGArgs {
  const u16* A; const u16* B; u16* C;
  const int* tokmap; const int2* blkmap; const int* nbrow;
};

#define STG(d, kt, h, l) \
  __builtin_amdgcn_global_load_lds( \
    (const __attribute__((address_space(1))) void*)(gs[(h)*2+(l)] + (size_t)(kt)*64), \
    (__attribute__((address_space(3))) void*)&lds[(d)*32768 + (h)*8192 + (tid + (l)*512)*8], \
    16, 0, 0)

template <int MODE>
__global__ __launch_bounds__(512, 1) void gemm256g(GemmGArgs g) {
  const int bid = blockIdx.x;
  const int logical = (bid & 7) * 28 + (bid >> 3);
  const int br = logical >> 2;
  if (br >= g.nbrow[0]) return;
  const int2 bm = g.blkmap[br];
  const int e = bm.x;
  const int m0 = bm.y;
  const int n0 = (logical & 3) * 256;
  const int tid = threadIdx.x;
  const int lane = tid & 63;
  const int wave = tid >> 6;     // 0..7
  const int wr = wave >> 2;      // 0..1
  const int wc = wave & 3;       // 0..3

  constexpr int K = MODE ? 1024 : 512;
  const u16* Bp = g.B + (size_t)e * (MODE ? 1048576 : 524288);

  __shared__ u16 lds[65536];

  // Swizzle: physical 16B-granule p of row r holds logical granule p^(r&7)
  // (pre-swizzled global source; gload_lds dest linear; readers XOR).
  const u16* gs[8];
#pragma unroll
  for (int h = 0; h < 4; h++)
#pragma unroll
    for (int l = 0; l < 2; l++) {
      const int slot = tid + l * 512;
      const int row = slot >> 3, p = slot & 7;
      const int glog = p ^ (row & 7);
      const u16* basep;
      if (h < 2) {
        const int grow = m0 + h * 128 + row;
        const int t = MODE ? g.tokmap[grow] : grow;
        basep = g.A + (size_t)t * K;
      } else {
        basep = Bp + (size_t)(n0 + (h - 2) * 128 + row) * K;
      }
      gs[h * 2 + l] = basep + glog * 8;
    }

  f4v acc[8][4];
#pragma unroll
  for (int i = 0; i < 8; i++)
#pragma unroll
    for (int j = 0; j < 4; j++) acc[i][j] = (f4v){0.f, 0.f, 0.f, 0.f};

  const int q = lane >> 4;
  const int lx = lane & 7;
  const int l15 = lane & 15;
  const int arowbase = wr * 8192 + l15 * 64;
  const int browbase = (2 + (wc >> 1)) * 8192 + (((wc & 1) << 6) + l15) * 64;

  // prologue: stage tile 0, batch order b1..b4
  STG(0, 0, 2, 0); STG(0, 0, 2, 1);   // b1: B-lo
  STG(0, 0, 3, 0); STG(0, 0, 3, 1);   // b2: B-hi
  STG(0, 0, 0, 0); STG(0, 0, 1, 0);   // b3: A-sub0
  STG(0, 0, 0, 1); STG(0, 0, 1, 1);   // b4: A-sub1

  constexpr int nt = K >> 6;
  bfrag bfr[2][4];
  for (int kt = 0; kt < nt; ++kt) {
    const int d = kt & 1;
    const int dn = d ^ 1;
    const bool more = (kt + 1 < nt);
    const int ab = d * 32768 + arowbase;
    const int bb = d * 32768 + browbase;

    // ---- phase A ----
    asm volatile("s_waitcnt vmcnt(2)" ::: "memory");
    __builtin_amdgcn_s_barrier();
    if (more) { STG(dn, kt + 1, 2, 0); STG(dn, kt + 1, 2, 1);
                STG(dn, kt + 1, 3, 0); STG(dn, kt + 1, 3, 1); }
    {
      bfrag afr[4][2];
#pragma unroll
      for (int kk = 0; kk < 2; kk++) {
        const int pa = ((kk * 4 + q) ^ lx) << 3;
#pragma unroll
        for (int mi = 0; mi < 4; mi++) afr[mi][kk] = *(const bfrag*)&lds[ab + mi * 1024 + pa];
#pragma unroll
        for (int ni = 0; ni < 4; ni++) bfr[kk][ni] = *(const bfrag*)&lds[bb + ni * 1024 + pa];
      }
      __builtin_amdgcn_s_setprio(1);
#pragma unroll
      for (int kk = 0; kk < 2; kk++)
#pragma unroll
        for (int mi = 0; mi < 4; mi++)
#pragma unroll
          for (int ni = 0; ni < 4; ni++)
            acc[mi][ni] = __builtin_amdgcn_mfma_f32_16x16x32_bf16(afr[mi][kk], bfr[kk][ni], acc[mi][ni], 0, 0, 0);
      __builtin_amdgcn_s_setprio(0);
    }

    // ---- phase B ----
    if (more) asm volatile("s_waitcnt vmcnt(4)" ::: "memory");
    else      asm volatile("s_waitcnt vmcnt(0)" ::: "memory");
    __builtin_amdgcn_s_barrier();
    if (more) { STG(dn, kt + 1, 0, 0); STG(dn, kt + 1, 1, 0);
                STG(dn, kt + 1, 0, 1); STG(dn, kt + 1, 1, 1); }
    {
      bfrag afr[4][2];
#pragma unroll
      for (int kk = 0; kk < 2; kk++) {
        const int pa = ((kk * 4 + q) ^ lx) << 3;
#pragma unroll
        for (int mi = 0; mi < 4; mi++) afr[mi][kk] = *(const bfrag*)&lds[ab + (mi + 4) * 1024 + pa];
      }
      __builtin_amdgcn_s_setprio(1);
#pragma unroll
      for (int kk = 0; kk < 2; kk++)
#pragma unroll
        for (int mi = 0; mi < 4; mi++)
#pragma unroll
          for (int ni = 0; ni < 4; ni++)
            acc[mi + 4][ni] = __builtin_amdgcn_mfma_f32_16x16x32_bf16(afr[mi][kk], bfr[kk][ni], acc[mi + 4][ni], 0, 0, 0);
      __builtin_amdgcn_s_setprio(0);
    }
  }
  __syncthreads();   // drain + protect LDS reuse in epilogue

  const int crow0 = m0 + wr * 128 + q * 4;

  if (MODE == 1) {
    // fused h2 epilogue: y3 (wc>=2) -> LDS bf16 [256][136] (padded), h2 = y1*sigmoid(y3)
    u16* stage = lds;
    const int lrow0 = wr * 128 + q * 4;
    if (wc >= 2) {
      const int lc = (wc - 2) * 64 + l15;
#pragma unroll
      for (int mi = 0; mi < 8; mi++)
#pragma unroll
        for (int ni = 0; ni < 4; ni++)
#pragma unroll
          for (int r = 0; r < 4; r++)
            stage[(lrow0 + mi * 16 + r) * 136 + lc + ni * 16] = f2bf(acc[mi][ni][r]);
    }
    __syncthreads();
    if (wc < 2) {
      const int lc = wc * 64 + l15;
      const int fbase = (n0 >> 1) + lc;
#pragma unroll
      for (int mi = 0; mi < 8; mi++)
#pragma unroll
        for (int r = 0; r < 4; r++) {
          const int rowg = crow0 + mi * 16 + r;
          const int lr = lrow0 + mi * 16 + r;
#pragma unroll
          for (int ni = 0; ni < 4; ni++) {
            float y1 = acc[mi][ni][r];
            float y3 = bf2f(stage[lr * 136 + lc + ni * 16]);
            float h = y1 / (1.f + __expf(-y3));
            g.C[(size_t)rowg * FDIM + fbase + ni * 16] = f2bf(h);
          }
        }
    }
  } else {
    const int ccol0 = n0 + wc * 64 + l15;
#pragma unroll
    for (int mi = 0; mi < 8; mi++)
#pragma unroll
      for (int ni = 0; ni < 4; ni++) {
        const int col = ccol0 + ni * 16;
#pragma unroll
        for (int r = 0; r < 4; r++)
          g.C[(size_t)(crow0 + mi * 16 + r) * 1024 + col] = f2bf(acc[mi][ni][r]);
      }
  }
}

// ============ mid kernel: gemm64 (router hidden) + merged LoRA fold, one launch ============
struct MidArgs {
  const u16* A64; const u16* B64; u16* C64; const float* bias64;
  const u16* A0; const u16* B0;
  const u16* Wb;
  u16* C13; u16* C2e;
  const float* amaxP;      // [27][128]
};

__global__ __launch_bounds__(256) void mid_kernel(MidArgs g) {
  __shared__ u16 smem[25600];
  __shared__ float s_sw;
  const int bid = blockIdx.x;
  const int tid = threadIdx.x;
  const int lane = tid & 63;
  const int wave = tid >> 6;

  if (bid < 256) {
    const int wr = wave >> 1, wc = wave & 1;
    const int m0 = (bid & 63) * 64, n0 = (bid >> 6) * 64;
    const int K = DDIM, N = HDIM;
    u16* As = smem;
    u16* Bs = smem + 2048;

    const int ldrow = tid >> 2;
    const int swzcol = (((tid & 3) ^ ((tid >> 3) & 3)) << 3);
    const u16* ga = g.A64 + (size_t)(m0 + ldrow) * K + swzcol;
    const u16* gb = g.B64 + (size_t)(n0 + ldrow) * K + swzcol;

    f4v acc[2][2];
#pragma unroll
    for (int i = 0; i < 2; i++)
#pragma unroll
      for (int j = 0; j < 2; j++) acc[i][j] = (f4v){0.f, 0.f, 0.f, 0.f};

    const int rbase = lane & 15;
    const int q = lane >> 4;
    const int pg = (q ^ ((rbase >> 1) & 3)) << 3;
    const int arow = (wr << 5) + rbase;
    const int brow = (wc << 5) + rbase;

    for (int kt = 0; kt < K; kt += 32) {
      __builtin_amdgcn_global_load_lds((const __attribute__((address_space(1))) void*)(ga),
          (__attribute__((address_space(3))) void*)&As[tid * 8], 16, 0, 0);
      __builtin_amdgcn_global_load_lds((const __attribute__((address_space(1))) void*)(gb),
          (__attribute__((address_space(3))) void*)&Bs[tid * 8], 16, 0, 0);
      ga += 32; gb += 32;
      __syncthreads();
      bfrag af[2], bf[2];
#pragma unroll
      for (int mi = 0; mi < 2; mi++)
        af[mi] = *(const bfrag*)&As[(arow + mi * 16) * 32 + pg];
#pragma unroll
      for (int ni = 0; ni < 2; ni++)
        bf[ni] = *(const bfrag*)&Bs[(brow + ni * 16) * 32 + pg];
#pragma unroll
      for (int mi = 0; mi < 2; mi++)
#pragma unroll
        for (int ni = 0; ni < 2; ni++)
          acc[mi][ni] = __builtin_amdgcn_mfma_f32_16x16x32_bf16(af[mi], bf[ni], acc[mi][ni], 0, 0, 0);
      __syncthreads();
    }

    const int crow0 = m0 + (wr << 5) + ((lane >> 4) << 2);
    const int ccol0 = n0 + (wc << 5) + (lane & 15);
#pragma unroll
    for (int mi = 0; mi < 2; mi++)
#pragma unroll
      for (int ni = 0; ni < 2; ni++) {
        const int n = ccol0 + ni * 16;
        const float b = g.bias64[n];
#pragma unroll
        for (int r = 0; r < 4; r++) {
          float v = fmaxf(acc[mi][ni][r] + b, 0.f);
          g.C64[(size_t)(crow0 + mi * 16 + r) * N + n] = f2bf(v);
        }
      }
    return;
  }

  // fold: C_bf16 = fq(Wraw, sW[z]) + A@B^T
  const int fid = bid - 256;
  const int z = fid >> 6;
  const int rem = fid & 63;
  const int bx = rem & 7, by = rem >> 3;
  const bool is13 = z < 18;
  if (is13 ? (bx >= 4) : (by >= 4)) return;
  const int N = is13 ? 1024 : 512;
  const int K = 64;
  const u16* Ap = is13 ? g.A0 + (size_t)z * 32768 : g.A0 + 589824 + (size_t)(z - 18) * 65536;
  const u16* Bp = is13 ? g.B0 + (size_t)z * 65536 : g.B0 + 1179648 + (size_t)(z - 18) * 32768;
  const u16* Wf = g.Wb + (size_t)z * 524288;
  u16* Cb; int flag;
  if (is13) {
    const int slot = (z >= 16) ? 8 : (z & 7);
    Cb = g.C13 + (size_t)slot * 1048576;
    flag = (z >= 8 && z < 16) || z == 17 ? 2 : 1;
  } else {
    Cb = g.C2e + (size_t)(z - 18) * 524288;
    flag = 0;
  }

  const int wr = wave >> 1, wc = wave & 1;
  const int m0 = bx * 128, n0 = by * 128;
  u16* As = smem;
  u16* Bs = smem + 4096;
  u16* stage = smem + 8192;

  if (wave == 0) {
    float m = fmaxf(g.amaxP[z * 128 + lane], g.amaxP[z * 128 + 64 + lane]);
#pragma unroll
    for (int off = 32; off > 0; off >>= 1) m = fmaxf(m, __shfl_xor(m, off));
    if (lane == 0) s_sw = fmaxf(m / 127.f, 1e-8f);
  }

  const int ldrow = tid >> 2;
  const int swzcol = (((tid & 3) ^ ((tid >> 3) & 3)) << 3);
  const u16* ga = Ap + (size_t)(m0 + ldrow) * K + swzcol;
  const u16* gb = Bp + (size_t)(n0 + ldrow) * K + swzcol;
  const size_t rowstep = (size_t)64 * K;

  f4v acc[4][4];
#pragma unroll
  for (int i = 0; i < 4; i++)
#pragma unroll
    for (int j = 0; j < 4; j++) acc[i][j] = (f4v){0.f, 0.f, 0.f, 0.f};

  const int rbase = lane & 15;
  const int q = lane >> 4;
  const int pg = (q ^ ((rbase >> 1) & 3)) << 3;
  const int arow = (wr << 6) + rbase;
  const int brow = (wc << 6) + rbase;

  for (int kt = 0; kt < K; kt += 32) {
    __builtin_amdgcn_global_load_lds((const __attribute__((address_space(1))) void*)(ga),
        (__attribute__((address_space(3))) void*)&As[tid * 8], 16, 0, 0);
    __builtin_amdgcn_global_load_lds((const __attribute__((address_space(1))) void*)(ga + rowstep),
        (__attribute__((address_space(3))) void*)&As[(256 + tid) * 8], 16, 0, 0);
    __builtin_amdgcn_global_load_lds((const __attribute__((address_space(1))) void*)(gb),
        (__attribute__((address_space(3))) void*)&Bs[tid * 8], 16, 0, 0);
    __builtin_amdgcn_global_load_lds((const __attribute__((address_space(1))) void*)(gb + rowstep),
        (__attribute__((address_space(3))) void*)&Bs[(256 + tid) * 8], 16, 0, 0);
    ga += 32; gb += 32;
    __syncthreads();
    bfrag af[4], bf[4];
#pragma unroll
    for (int mi = 0; mi < 4; mi++)
      af[mi] = *(const bfrag*)&As[(arow + mi * 16) * 32 + pg];
#pragma unroll
    for (int ni = 0; ni < 4; ni++)
      bf[ni] = *(const bfrag*)&Bs[(brow + ni * 16) * 32 + pg];
#pragma unroll
    for (int mi = 0; mi < 4; mi++)
#pragma unroll
      for (int ni = 0; ni < 4; ni++)
        acc[mi][ni] = __builtin_amdgcn_mfma_f32_16x16x32_bf16(af[mi], bf[ni], acc[mi][ni], 0, 0, 0);
    __syncthreads();
  }

  const int lrow0 = (wr << 6) + ((lane >> 4) << 2);
  const int lcol0 = (wc << 6) + (lane & 15);
#pragma unroll
  for (int mi = 0; mi < 4; mi++)
#pragma unroll
    for (int ni = 0; ni < 4; ni++) {
      const int n = lcol0 + ni * 16;
#pragma unroll
      for (int r = 0; r < 4; r++)
        stage[(lrow0 + mi * 16 + r) * 136 + n] = f2bf(acc[mi][ni][r]);
    }
  __syncthreads();
  const float sw = s_sw;

  const int dm0 = flag ? (((m0 >> 7) << 8) + (flag == 2 ? 128 : 0)) : m0;
#pragma unroll
  for (int j = 0; j < 8; j++) {
    const int s = j * 256 + tid;
    const int lr = s >> 4;
    const int n8 = (s & 15) << 3;
    const u16x8 wv = *(const u16x8*)&Wf[(size_t)(m0 + lr) * N + n0 + n8];
    const bfrag sv = *(const bfrag*)&stage[lr * 136 + n8];
    u16x8 o;
#pragma unroll
    for (int k = 0; k < 8; k++)
      o[k] = f2bf(fq1(bf2f(wv[k]), sw) + bf2f((u16)sv[k]));
    *(u16x8*)&Cb[(size_t)(dm0 + lr) * N + n0 + n8] = o;
  }
}

// ---------------- prep: amax+convW (blocks 0..3455) + conversions (3456..7551) ----------------
struct PrepArgs {
  const float* W[27]; u16* Wraw; float* amaxP;
  const float* xf; u16* xfb;
  const float* p1w; u16* p1wb;
  const float* Asrc[27]; u16* Adst;
  const float* Bsrc[27]; u16* Bdst;
};
__global__ __launch_bounds__(256) void prep_kernel(PrepArgs a) {
  const int bid = blockIdx.x;
  const int tid = threadIdx.x;
  if (bid < 3456) {
    const int t = bid >> 7;
    const int bx = bid & 127;
    const float4* src = (const float4*)a.W[t];
    ushort4* dst = (ushort4*)(a.Wraw + (size_t)t * 524288);
    const int i0 = bx * 256 + tid;
    float4 v0 = src[i0];
    float4 v1 = src[i0 + 32768];
    float4 v2 = src[i0 + 65536];
    float4 v3 = src[i0 + 98304];
    ushort4 o0, o1, o2, o3;
    o0.x = f2bf(v0.x); o0.y = f2bf(v0.y); o0.z = f2bf(v0.z); o0.w = f2bf(v0.w);
    o1.x = f2bf(v1.x); o1.y = f2bf(v1.y); o1.z = f2bf(v1.z); o1.w = f2bf(v1.w);
    o2.x = f2bf(v2.x); o2.y = f2bf(v2.y); o2.z = f2bf(v2.z); o2.w = f2bf(v2.w);
    o3.x = f2bf(v3.x); o3.y = f2bf(v3.y); o3.z = f2bf(v3.z); o3.w = f2bf(v3.w);
    dst[i0] = o0; dst[i0 + 32768] = o1; dst[i0 + 65536] = o2; dst[i0 + 98304] = o3;
    float m01 = fmaxf(fmaxf(fabsf(v0.x), fabsf(v0.y)), fmaxf(fabsf(v0.z), fabsf(v0.w)));
    float m11 = fmaxf(fmaxf(fabsf(v1.x), fabsf(v1.y)), fmaxf(fabsf(v1.z), fabsf(v1.w)));
    float m21 = fmaxf(fmaxf(fabsf(v2.x), fabsf(v2.y)), fmaxf(fabsf(v2.z), fabsf(v2.w)));
    float m31 = fmaxf(fmaxf(fabsf(v3.x), fabsf(v3.y)), fmaxf(fabsf(v3.z), fabsf(v3.w)));
    float lmax = fmaxf(fmaxf(m01, m11), fmaxf(m21, m31));
#pragma unroll
    for (int off = 32; off > 0; off >>= 1) lmax = fmaxf(lmax, __shfl_xor(lmax, off));
    __shared__ float wm[4];
    if ((tid & 63) == 0) wm[tid >> 6] = lmax;
    __syncthreads();
    if (tid == 0)
      a.amaxP[t * 128 + bx] = fmaxf(fmaxf(wm[0], wm[1]), fmaxf(wm[2], wm[3]));
    return;
  }
  const int cid = bid - 3456;
  const int slice = cid >> 10;
  const int g0 = (cid & 1023) * 256 + tid;
  const int stride = 262144;
  if (slice == 0) {
    for (int i = g0; i < 1048576; i += stride) {
      float4 v = ((const float4*)a.xf)[i];
      ushort4 o; o.x = f2bf(v.x); o.y = f2bf(v.y); o.z = f2bf(v.z); o.w = f2bf(v.w);
      ((ushort4*)a.xfb)[i] = o;
    }
  } else if (slice == 1) {
    for (int i = g0; i < 65536; i += stride) {
      float4 v = ((const float4*)a.p1w)[i];
      ushort4 o; o.x = f2bf(v.x); o.y = f2bf(v.y); o.z = f2bf(v.z); o.w = f2bf(v.w);
      ((ushort4*)a.p1wb)[i] = o;
    }
  } else if (slice == 2) {
    for (int i = g0; i < 1179648; i += stride) {
      int t, off;
      if (i < 589824) { t = i >> 15; off = i & 32767; }
      else { int j = i - 589824; t = 18 + (j >> 16); off = j & 65535; }
      a.Adst[i] = f2bf(a.Asrc[t][off]);
    }
  } else {
    for (int i = g0; i < 1474560; i += stride) {
      int t, src;
      if (i < 1179648) { t = i >> 16; int off = i & 65535; src = (off & 63) * 1024 + (off >> 6); }
      else { int j = i - 1179648; t = 18 + (j >> 15); int off = j & 32767; src = (off & 63) * 512 + (off >> 6); }
      a.Bdst[i] = f2bf(a.Bsrc[t][src]);
    }
  }
}

// ---------------- router: logits (16 tokens/block) + topk fused ----------------
struct RouterArgs {
  const float* xf; const u16* ph;
  const float* sw; const float* sb;
  const float* p2w; const float* p2b;
  int* idx2; float2* wb;
  float* partials;   // [256][10]
  int* histArr;      // [256][8]
};
__global__ __launch_bounds__(256) void router_kernel(RouterArgs a) {
  __shared__ float sw[8][1024];
  __shared__ float p2[8][256];
  __shared__ float blog[16][8];
  __shared__ float plog[16][8];
  __shared__ int hist[8];
  const int tid = threadIdx.x;
  {
    const float4* s0 = (const float4*)a.sw;
    float4* d0 = (float4*)&sw[0][0];
    for (int i = tid; i < 2048; i += 256) d0[i] = s0[i];
    const float4* s1 = (const float4*)a.p2w;
    float4* d1 = (float4*)&p2[0][0];
    for (int i = tid; i < 512; i += 256) d1[i] = s1[i];
  }
  if (tid < 8) hist[tid] = 0;
  __syncthreads();
  const int tl = tid >> 4, s = tid & 15;
  const int token = blockIdx.x * 16 + tl;
  {
    float acc[8] = {0,0,0,0,0,0,0,0}, pacc[8] = {0,0,0,0,0,0,0,0};
    const float4* xrow = (const float4*)(a.xf + (size_t)token * 1024);
    for (int i = 0; i < 16; i++) {
      const int d4 = i * 16 + s;
      float4 xv = xrow[d4];
#pragma unroll
      for (int e = 0; e < 8; e++) {
        float4 wv = ((const float4*)&sw[e][0])[d4];
        acc[e] += xv.x * wv.x + xv.y * wv.y + xv.z * wv.z + xv.w * wv.w;
      }
    }
    const u16* phrow = a.ph + (size_t)token * 256;
    for (int i = 0; i < 16; i++) {
      const int h = i * 16 + s;
      float pv = bf2f(phrow[h]);
#pragma unroll
      for (int e = 0; e < 8; e++) pacc[e] += pv * p2[e][h];
    }
#pragma unroll
    for (int off = 8; off > 0; off >>= 1)
#pragma unroll
      for (int e = 0; e < 8; e++) {
        acc[e] += __shfl_xor(acc[e], off);
        pacc[e] += __shfl_xor(pacc[e], off);
      }
    if (s == 0) {
#pragma unroll
      for (int e = 0; e < 8; e++) {
        blog[tl][e] = acc[e] + a.sb[e];
        plog[tl][e] = pacc[e] + a.p2b[e];
      }
    }
  }
  __syncthreads();

  float vals[10];
#pragma unroll
  for (int v = 0; v < 10; v++) vals[v] = 0.f;
  if (tid < 16) {
    const int tok = blockIdx.x * 16 + tid;
    float b[8], p[8];
#pragma unroll
    for (int e = 0; e < 8; e++) { b[e] = blog[tid][e]; p[e] = plog[tid][e]; }
    float pm = p[0];
#pragma unroll
    for (int e = 1; e < 8; e++) pm = fmaxf(pm, p[e]);
    float pe[8], psum = 0.f;
#pragma unroll
    for (int e = 0; e < 8; e++) { pe[e] = expf(p[e] - pm); psum += pe[e]; }
    const float pinv = 1.f / psum;
    float sl[8];
#pragma unroll
    for (int e = 0; e < 8; e++) sl[e] = (b[e] + pe[e] * pinv) * 0.5f;
    float sm = sl[0];
#pragma unroll
    for (int e = 1; e < 8; e++) sm = fmaxf(sm, sl[e]);
    float sc[8], ssum = 0.f;
#pragma unroll
    for (int e = 0; e < 8; e++) { sc[e] = expf(sl[e] - sm); ssum += sc[e]; }
    const float sinv = 1.f / ssum;
    float ent = 0.f;
#pragma unroll
    for (int e = 0; e < 8; e++) { float v = sc[e] * sinv; sc[e] = v; ent -= v * logf(v + 1e-6f); }
    float bm = b[0];
#pragma unroll
    for (int e = 1; e < 8; e++) bm = fmaxf(bm, b[e]);
    float zs = 0.f;
#pragma unroll
    for (int e = 0; e < 8; e++) zs += expf(b[e] - bm);
    const float lse = logf(zs) + bm;
    float m1 = -1e30f, m2 = -1e30f; int i1 = 0, i2 = 0;
#pragma unroll
    for (int e = 0; e < 8; e++) {
      float v = sc[e];
      if (v > m1) { m2 = m1; i2 = i1; m1 = v; i1 = e; }
      else if (v > m2) { m2 = v; i2 = e; }
    }
    a.idx2[tok] = i1 | (i2 << 8);
    a.wb[tok] = make_float2(m1, m2);
    atomicAdd(&hist[i1], 1);
    atomicAdd(&hist[i2], 1);
    vals[0] = ent; vals[1] = lse * lse;
    vals[2 + i1] = m1; vals[2 + i2] = m2;
  }
  if (tid < 64) {
#pragma unroll
    for (int v = 0; v < 10; v++)
#pragma unroll
      for (int off = 32; off > 0; off >>= 1) vals[v] += __shfl_down(vals[v], off);
    if (tid == 0)
#pragma unroll
      for (int v = 0; v < 10; v++) a.partials[blockIdx.x * 10 + v] = vals[v];
  }
  __syncthreads();
  if (tid < 8) a.histArr[blockIdx.x * 8 + tid] = hist[tid];
}

// ---------------- compaction + setup + losses (9 blocks, cooperative reductions) ----------------
__global__ __launch_bounds__(256) void compact_setup(const int* idx2, const int* histArr,
                                                     int2* blkmap, int* nbrow, int* tokmap,
                                                     int* posb, const float* partials, float* tail) {
  const int e = blockIdx.x;
  const int tid = threadIdx.x;
  const int lane = tid & 63, wv = tid >> 6;
  __shared__ int scnt[8];
  __shared__ int wcnt[4][8];

  {
    int local[8];
#pragma unroll
    for (int i = 0; i < 8; i++) local[i] = histArr[tid * 8 + i];
#pragma unroll
    for (int i = 0; i < 8; i++) {
      int v = local[i];
#pragma unroll
      for (int off = 32; off > 0; off >>= 1) v += __shfl_down(v, off);
      if (lane == 0) wcnt[wv][i] = v;
    }
  }
  __syncthreads();
  if (tid < 8) scnt[tid] = wcnt[0][tid] + wcnt[1][tid] + wcnt[2][tid] + wcnt[3][tid];
  __syncthreads();

  if (e == 8) {
    __shared__ float wpart[4][10];
    float pv[10];
#pragma unroll
    for (int v = 0; v < 10; v++) pv[v] = partials[tid * 10 + v];
#pragma unroll
    for (int v = 0; v < 10; v++) {
      float t = pv[v];
#pragma unroll
      for (int off = 32; off > 0; off >>= 1) t += __shfl_down(t, off);
      if (lane == 0) wpart[wv][v] = t;
    }
    __syncthreads();
    if (tid == 0) {
      float pt[10];
#pragma unroll
      for (int v = 0; v < 10; v++)
        pt[v] = wpart[0][v] + wpart[1][v] + wpart[2][v] + wpart[3][v];
      const float ent = pt[0], z = pt[1];
      float us[8];
      for (int ex = 0; ex < 8; ex++) us[ex] = pt[2 + ex];
      float tot = 0.f;
      for (int ex = 0; ex < 8; ex++) tot += us[ex];
      const float meanu = tot / 8.f;
      float uf[8], mu = 0.f;
      for (int ex = 0; ex < 8; ex++) { uf[ex] = us[ex] / (meanu + 1e-6f); mu += uf[ex]; }
      mu /= 8.f;
      float var = 0.f;
      for (int ex = 0; ex < 8; ex++) { float d = uf[ex] - mu; var += d * d; }
      var /= 7.f;
      const float bl = 0.3f * var - 0.1f * (ent / 4096.f) + 1e-4f * (z / 4096.f);
      for (int ex = 0; ex < 8; ex++) tail[ex] = us[ex];
      tail[8] = bl; tail[9] = 0.f; tail[10] = 0.f;
      int o = 0, nb = 16;
      for (int i = 0; i < 16; i++) blkmap[i] = make_int2(8, i * 256);
      for (int ex = 0; ex < 8; ex++) {
        const int nbe = (scnt[ex] + 255) >> 8;
        for (int i = 0; i < nbe; i++) blkmap[nb++] = make_int2(ex, 4096 + o + i * 256);
        o += nbe << 8;
      }
      nbrow[0] = nb;
    }
    for (int t = tid; t < 4096; t += 256) tokmap[t] = t;
    return;
  }

  __shared__ int wtot[4];
  __shared__ int carry;
  if (tid == 0) carry = 0;
  __syncthreads();
  int off = 0;
  for (int i = 0; i < e; i++) off += ((scnt[i] + 255) >> 8) << 8;
  const int base = 4096 + off;
  for (int c = 0; c < 16; c++) {
    const int t = c * 256 + tid;
    const int ii = idx2[t];
    const int i1 = ii & 255, i2 = ii >> 8;
    const int flag = (i1 == e || i2 == e) ? 1 : 0;
    const unsigned long long m = __ballot(flag);
    const int pre = __popcll(m & ((1ull << lane) - 1ull));
    if (lane == 63) wtot[wv] = pre + flag;
    __syncthreads();
    int wbase = 0;
    for (int i = 0; i < wv; i++) wbase += wtot[i];
    if (flag) {
      const int row = base + carry + wbase + pre;
      tokmap[row] = t;
      posb[t * 2 + (i2 == e ? 1 : 0)] = row;
    }
    __syncthreads();
    if (tid == 0) carry += wtot[0] + wtot[1] + wtot[2] + wtot[3];
    __syncthreads();
  }
  const int ce = scnt[e];
  const int pend = ((ce + 255) >> 8) << 8;
  for (int r = ce + tid; r < pend; r += 256) tokmap[base + r] = 0;
}

// ---------------- combine: out[t] = y2c[t] + w1*y2c[p1] + w2*y2c[p2] ----------------
__global__ __launch_bounds__(256) void combine_g(const u16* y2c, const int* posb,
                                                 const float2* wb, float* out) {
  const int t = blockIdx.x;
  const int c = threadIdx.x;
  const float2 w = wb[t];
  const int p1 = posb[t * 2], p2 = posb[t * 2 + 1];
  ushort4 s = ((const ushort4*)(y2c + (size_t)t * 1024))[c];
  ushort4 a = ((const ushort4*)(y2c + (size_t)p1 * 1024))[c];
  ushort4 b = ((const ushort4*)(y2c + (size_t)p2 * 1024))[c];
  float4 o;
  o.x = bf2f(s.x) + w.x * bf2f(a.x) + w.y * bf2f(b.x);
  o.y = bf2f(s.y) + w.x * bf2f(a.y) + w.y * bf2f(b.y);
  o.z = bf2f(s.z) + w.x * bf2f(a.z) + w.y * bf2f(b.z);
  o.w = bf2f(s.w) + w.x * bf2f(a.w) + w.y * bf2f(b.w);
  ((float4*)(out + (size_t)t * 1024))[c] = o;
}

// ---------------- host ----------------
extern "C" void kernel_launch(void* const* d_in, const int* in_sizes, int n_in,
                              void* d_out, int out_size, void* d_ws, size_t ws_size,
                              hipStream_t stream) {
  const float* x = (const float*)d_in[0];
  const float* scorer_w = (const float*)d_in[1];
  const float* scorer_b = (const float*)d_in[2];
  const float* p1_w = (const float*)d_in[3];
  const float* p1_b = (const float*)d_in[4];
  const float* p2_w = (const float*)d_in[5];
  const float* p2_b = (const float*)d_in[6];
  const float* ew1_w = (const float*)d_in[7];
  const float* ew1_a = (const float*)d_in[8];
  const float* ew1_b = (const float*)d_in[9];
  const float* ew2_w = (const float*)d_in[10];
  const float* ew2_a = (const float*)d_in[11];
  const float* ew2_b = (const float*)d_in[12];
  const float* ew3_w = (const float*)d_in[13];
  const float* ew3_a = (const float*)d_in[14];
  const float* ew3_b = (const float*)d_in[15];
  const float* s1_w = (const float*)d_in[16];
  const float* s1_a = (const float*)d_in[17];
  const float* s1_b = (const float*)d_in[18];
  const float* s2_w = (const float*)d_in[19];
  const float* s2_a = (const float*)d_in[20];
  const float* s2_b = (const float*)d_in[21];
  const float* s3_w = (const float*)d_in[22];
  const float* s3_a = (const float*)d_in[23];
  const float* s3_b = (const float*)d_in[24];
  float* outf = (float*)d_out;

  char* w = (char*)d_ws;
  auto alloc = [&](size_t bytes) { char* p = w; w += (bytes + 255) & ~(size_t)255; return p; };
  u16* xfb  = (u16*)alloc((size_t)TTOK * DDIM * 2);
  u16* ph   = (u16*)alloc((size_t)TTOK * HDIM * 2);
  u16* p1wb = (u16*)alloc((size_t)HDIM * DDIM * 2);
  u16* Adst = (u16*)alloc((size_t)1179648 * 2);
  u16* Bdst = (u16*)alloc((size_t)1474560 * 2);
  u16* Wraw = (u16*)alloc((size_t)27 * 524288 * 2);
  u16* W13  = (u16*)alloc((size_t)9 * 1024 * 1024 * 2);
  u16* W2e  = (u16*)alloc((size_t)9 * 1024 * 512 * 2);
  u16* h2c  = (u16*)alloc((size_t)CROWS * FDIM * 2);
  u16* y2c  = (u16*)alloc((size_t)CROWS * DDIM * 2);
  float* partials = (float*)alloc(256 * 10 * 4);
  float* amaxP = (float*)alloc(27 * 128 * 4);
  int* histArr = (int*)alloc(256 * 8 * 4);
  int2* blkmap = (int2*)alloc(64 * 8);
  int* nbrow  = (int*)alloc(4);
  int* tokmap = (int*)alloc(CROWS * 4);
  int* posb   = (int*)alloc(TTOK * 2 * 4);
  int* idx2   = (int*)alloc(TTOK * 4);
  float2* wb  = (float2*)alloc(TTOK * 8);

  // 1. prep: W amax partials + W->bf16 + all conversions
  {
    PrepArgs a{};
    for (int e = 0; e < 8; e++) {
      a.W[e] = ew1_w + (size_t)e * 524288;
      a.W[8 + e] = ew3_w + (size_t)e * 524288;
      a.W[18 + e] = ew2_w + (size_t)e * 524288;
      a.Asrc[e] = ew1_a + (size_t)e * 32768;
      a.Asrc[8 + e] = ew3_a + (size_t)e * 32768;
      a.Asrc[18 + e] = ew2_a + (size_t)e * 65536;
      a.Bsrc[e] = ew1_b + (size_t)e * 65536;
      a.Bsrc[8 + e] = ew3_b + (size_t)e * 65536;
      a.Bsrc[18 + e] = ew2_b + (size_t)e * 32768;
    }
    a.W[16] = s1_w; a.W[17] = s3_w; a.W[26] = s2_w;
    a.Asrc[16] = s1_a; a.Asrc[17] = s3_a; a.Asrc[26] = s2_a;
    a.Bsrc[16] = s1_b; a.Bsrc[17] = s3_b; a.Bsrc[26] = s2_b;
    a.Wraw = Wraw; a.amaxP = amaxP;
    a.xf = x; a.xfb = xfb; a.p1w = p1_w; a.p1wb = p1wb;
    a.Adst = Adst; a.Bdst = Bdst;
    hipLaunchKernelGGL(prep_kernel, dim3(7552), dim3(256), 0, stream, a);
  }
  // 2. mid: router hidden gemm64 + merged LoRA fold
  {
    MidArgs g{};
    g.A64 = xfb; g.B64 = p1wb; g.C64 = ph; g.bias64 = p1_b;
    g.A0 = Adst; g.B0 = Bdst; g.Wb = Wraw; g.C13 = W13; g.C2e = W2e; g.amaxP = amaxP;
    hipLaunchKernelGGL(mid_kernel, dim3(1984), dim3(256), 0, stream, g);
  }
  // 3. router: logits + topk fused
  {
    RouterArgs r{};
    r.xf = x; r.ph = ph; r.sw = scorer_w; r.sb = scorer_b;
    r.p2w = p2_w; r.p2b = p2_b;
    r.idx2 = idx2; r.wb = wb; r.partials = partials; r.histArr = histArr;
    hipLaunchKernelGGL(router_kernel, dim3(256), dim3(256), 0, stream, r);
  }
  // 4. compaction + setup + losses (9 blocks)
  hipLaunchKernelGGL(compact_setup, dim3(9), dim3(256), 0, stream,
                     idx2, histArr, blkmap, nbrow, tokmap, posb, partials,
                     outf + (size_t)TTOK * DDIM);
  // 5. y13 + fused h2 over gathered rows (counted-vmcnt schedule)
  {
    GemmGArgs g{xfb, W13, h2c, tokmap, blkmap, nbrow};
    hipLaunchKernelGGL(gemm256g<1>, dim3(224), dim3(512), 0, stream, g);
  }
  // 6. y2 over concat rows
  {
    GemmGArgs g{h2c, W2e, y2c, tokmap, blkmap, nbrow};
    hipLaunchKernelGGL(gemm256g<0>, dim3(224), dim3(512), 0, stream, g);
  }
  // 7. deterministic combine
  hipLaunchKernelGGL(combine_g, dim3(4096), dim3(256), 0, stream, y2c, posb, wb, outf);
}

// Round 19
// 147.125 us; speedup vs baseline: 1.0352x; 1.0352x over previous
//
#include <hip/hip_runtime.h>

#define TTOK 4096
#define DDIM 1024
#define FDIM 512
#define NEXP 8
#define HDIM 256
#define RLORA 64
#define CROWS 14336   // 4096 shared + up to 10240 padded expert rows

using u16 = unsigned short;
using f4v = __attribute__((ext_vector_type(4))) float;
using bfrag = __attribute__((ext_vector_type(8))) short;
using u16x8 = __attribute__((ext_vector_type(8))) unsigned short;

static __device__ __forceinline__ float bf2f(u16 u) {
  union { unsigned int u; float f; } x; x.u = ((unsigned int)u) << 16; return x.f;
}
static __device__ __forceinline__ u16 f2bf(float f) {
  union { float f; unsigned int u; } x; x.f = f;
  unsigned int r = (x.u + 0x7fffu + ((x.u >> 16) & 1u)) >> 16;
  return (u16)r;
}
static __device__ __forceinline__ float fq1(float t, float s) {
  float q = rintf(t / s);
  q = fminf(fmaxf(q, -128.f), 127.f);
  return q * s;
}

// ============ 256x256 BK=64 16-wave dbuf GEMM over gathered token rows ============
// (R17-proven best: 147.7us total.) 1024 threads = 16 waves (4M x 4N), 64x64 per
// wave, 4 waves/SIMD TLP. 1D grid (224 blocks) + chunked XCD swizzle:
// logical = (bid&7)*28 + (bid>>3); br = logical>>2, n0 = (logical&3)*256.
// NOTE: counted-vmcnt variants (R5, R18) were both neutral-to-negative; the
// 2-phase __syncthreads structure with 16-wave TLP is the best measured here.
struct GemmGArgs {
  const u16* A; const u16* B; u16* C;
  const int* tokmap; const int2* blkmap; const int* nbrow;
};

#define STAGE1(d, kt, h) \
  __builtin_amdgcn_global_load_lds( \
    (const __attribute__((address_space(1))) void*)(gs[h] + (size_t)(kt)*64), \
    (__attribute__((address_space(3))) void*)&lds[(d)*32768 + (h)*8192 + tid*8], \
    16, 0, 0)

template <int MODE>
__global__ __launch_bounds__(1024, 4) void gemm256g(GemmGArgs g) {
  const int bid = blockIdx.x;
  const int logical = (bid & 7) * 28 + (bid >> 3);
  const int br = logical >> 2;
  if (br >= g.nbrow[0]) return;
  const int2 bm = g.blkmap[br];
  const int e = bm.x;
  const int m0 = bm.y;
  const int n0 = (logical & 3) * 256;
  const int tid = threadIdx.x;
  const int lane = tid & 63;
  const int wave = tid >> 6;     // 0..15
  const int wr = wave >> 2;      // 0..3 (M quarter)
  const int wc = wave & 3;       // 0..3 (N quarter)

  constexpr int K = MODE ? 1024 : 512;
  const u16* Bp = g.B + (size_t)e * (MODE ? 1048576 : 524288);

  __shared__ u16 lds[65536];

  // Swizzle: physical 16B-granule p of row r holds logical granule p^(r&7)
  // (pre-swizzled global source; gload_lds dest linear; readers XOR).
  const u16* gs[4];
#pragma unroll
  for (int h = 0; h < 4; h++) {
    const int row = tid >> 3, p = tid & 7;
    const int glog = p ^ (row & 7);
    const u16* basep;
    if (h < 2) {
      const int grow = m0 + h * 128 + row;
      const int t = MODE ? g.tokmap[grow] : grow;
      basep = g.A + (size_t)t * K;
    } else {
      basep = Bp + (size_t)(n0 + (h - 2) * 128 + row) * K;
    }
    gs[h] = basep + glog * 8;
  }

  f4v acc[4][4];
#pragma unroll
  for (int i = 0; i < 4; i++)
#pragma unroll
    for (int j = 0; j < 4; j++) acc[i][j] = (f4v){0.f, 0.f, 0.f, 0.f};

  const int q = lane >> 4;
  const int lx = lane & 7;
  const int l15 = lane & 15;

#pragma unroll
  for (int h = 0; h < 4; h++) STAGE1(0, 0, h);
  __syncthreads();

  constexpr int nt = K >> 6;
  for (int kt = 0; kt < nt; ++kt) {
    const int d = kt & 1;
    const int dn = d ^ 1;
    const bool more = (kt + 1 < nt);
#pragma unroll
    for (int kk = 0; kk < 2; ++kk) {
      if (more) {
        if (kk == 0) { STAGE1(dn, kt + 1, 0); STAGE1(dn, kt + 1, 1); }
        else         { STAGE1(dn, kt + 1, 2); STAGE1(dn, kt + 1, 3); }
      }
      bfrag afr[4], bfr[4];
      const int pa = ((kk * 4 + q) ^ lx) << 3;
      const int abase = d * 32768 + (wr >> 1) * 8192 + (((wr & 1) << 6) + l15) * 64 + pa;
#pragma unroll
      for (int mi = 0; mi < 4; mi++) afr[mi] = *(const bfrag*)&lds[abase + mi * 1024];
      const int bbase = d * 32768 + (2 + (wc >> 1)) * 8192 + (((wc & 1) << 6) + l15) * 64 + pa;
#pragma unroll
      for (int ni = 0; ni < 4; ni++) bfr[ni] = *(const bfrag*)&lds[bbase + ni * 1024];
      __builtin_amdgcn_s_setprio(1);
#pragma unroll
      for (int mi = 0; mi < 4; mi++)
#pragma unroll
        for (int ni = 0; ni < 4; ni++)
          acc[mi][ni] = __builtin_amdgcn_mfma_f32_16x16x32_bf16(afr[mi], bfr[ni], acc[mi][ni], 0, 0, 0);
      __builtin_amdgcn_s_setprio(0);
    }
    __syncthreads();
  }

  const int crow0 = m0 + wr * 64 + q * 4;

  if (MODE == 1) {
    // fused h2 epilogue: y3 (wc>=2) -> LDS bf16 [256][136] (padded), h2 = y1*sigmoid(y3)
    u16* stage = lds;
    const int lrow0 = wr * 64 + q * 4;
    if (wc >= 2) {
      const int lc = (wc - 2) * 64 + l15;
#pragma unroll
      for (int mi = 0; mi < 4; mi++)
#pragma unroll
        for (int ni = 0; ni < 4; ni++)
#pragma unroll
          for (int r = 0; r < 4; r++)
            stage[(lrow0 + mi * 16 + r) * 136 + lc + ni * 16] = f2bf(acc[mi][ni][r]);
    }
    __syncthreads();
    if (wc < 2) {
      const int lc = wc * 64 + l15;
      const int fbase = (n0 >> 1) + lc;
#pragma unroll
      for (int mi = 0; mi < 4; mi++)
#pragma unroll
        for (int r = 0; r < 4; r++) {
          const int rowg = crow0 + mi * 16 + r;
          const int lr = lrow0 + mi * 16 + r;
#pragma unroll
          for (int ni = 0; ni < 4; ni++) {
            float y1 = acc[mi][ni][r];
            float y3 = bf2f(stage[lr * 136 + lc + ni * 16]);
            float h = y1 / (1.f + __expf(-y3));
            g.C[(size_t)rowg * FDIM + fbase + ni * 16] = f2bf(h);
          }
        }
    }
  } else {
    const int ccol0 = n0 + wc * 64 + l15;
#pragma unroll
    for (int mi = 0; mi < 4; mi++)
#pragma unroll
      for (int ni = 0; ni < 4; ni++) {
        const int col = ccol0 + ni * 16;
#pragma unroll
        for (int r = 0; r < 4; r++)
          g.C[(size_t)(crow0 + mi * 16 + r) * 1024 + col] = f2bf(acc[mi][ni][r]);
      }
  }
}

// ============ mid kernel: gemm64 (router hidden) + merged LoRA fold, one launch ============
struct MidArgs {
  const u16* A64; const u16* B64; u16* C64; const float* bias64;
  const u16* A0; const u16* B0;
  const u16* Wb;
  u16* C13; u16* C2e;
  const float* amaxP;      // [27][128]
};

__global__ __launch_bounds__(256) void mid_kernel(MidArgs g) {
  __shared__ u16 smem[25600];
  __shared__ float s_sw;
  const int bid = blockIdx.x;
  const int tid = threadIdx.x;
  const int lane = tid & 63;
  const int wave = tid >> 6;

  if (bid < 256) {
    const int wr = wave >> 1, wc = wave & 1;
    const int m0 = (bid & 63) * 64, n0 = (bid >> 6) * 64;
    const int K = DDIM, N = HDIM;
    u16* As = smem;
    u16* Bs = smem + 2048;

    const int ldrow = tid >> 2;
    const int swzcol = (((tid & 3) ^ ((tid >> 3) & 3)) << 3);
    const u16* ga = g.A64 + (size_t)(m0 + ldrow) * K + swzcol;
    const u16* gb = g.B64 + (size_t)(n0 + ldrow) * K + swzcol;

    f4v acc[2][2];
#pragma unroll
    for (int i = 0; i < 2; i++)
#pragma unroll
      for (int j = 0; j < 2; j++) acc[i][j] = (f4v){0.f, 0.f, 0.f, 0.f};

    const int rbase = lane & 15;
    const int q = lane >> 4;
    const int pg = (q ^ ((rbase >> 1) & 3)) << 3;
    const int arow = (wr << 5) + rbase;
    const int brow = (wc << 5) + rbase;

    for (int kt = 0; kt < K; kt += 32) {
      __builtin_amdgcn_global_load_lds((const __attribute__((address_space(1))) void*)(ga),
          (__attribute__((address_space(3))) void*)&As[tid * 8], 16, 0, 0);
      __builtin_amdgcn_global_load_lds((const __attribute__((address_space(1))) void*)(gb),
          (__attribute__((address_space(3))) void*)&Bs[tid * 8], 16, 0, 0);
      ga += 32; gb += 32;
      __syncthreads();
      bfrag af[2], bf[2];
#pragma unroll
      for (int mi = 0; mi < 2; mi++)
        af[mi] = *(const bfrag*)&As[(arow + mi * 16) * 32 + pg];
#pragma unroll
      for (int ni = 0; ni < 2; ni++)
        bf[ni] = *(const bfrag*)&Bs[(brow + ni * 16) * 32 + pg];
#pragma unroll
      for (int mi = 0; mi < 2; mi++)
#pragma unroll
        for (int ni = 0; ni < 2; ni++)
          acc[mi][ni] = __builtin_amdgcn_mfma_f32_16x16x32_bf16(af[mi], bf[ni], acc[mi][ni], 0, 0, 0);
      __syncthreads();
    }

    const int crow0 = m0 + (wr << 5) + ((lane >> 4) << 2);
    const int ccol0 = n0 + (wc << 5) + (lane & 15);
#pragma unroll
    for (int mi = 0; mi < 2; mi++)
#pragma unroll
      for (int ni = 0; ni < 2; ni++) {
        const int n = ccol0 + ni * 16;
        const float b = g.bias64[n];
#pragma unroll
        for (int r = 0; r < 4; r++) {
          float v = fmaxf(acc[mi][ni][r] + b, 0.f);
          g.C64[(size_t)(crow0 + mi * 16 + r) * N + n] = f2bf(v);
        }
      }
    return;
  }

  // fold: C_bf16 = fq(Wraw, sW[z]) + A@B^T
  const int fid = bid - 256;
  const int z = fid >> 6;
  const int rem = fid & 63;
  const int bx = rem & 7, by = rem >> 3;
  const bool is13 = z < 18;
  if (is13 ? (bx >= 4) : (by >= 4)) return;
  const int N = is13 ? 1024 : 512;
  const int K = 64;
  const u16* Ap = is13 ? g.A0 + (size_t)z * 32768 : g.A0 + 589824 + (size_t)(z - 18) * 65536;
  const u16* Bp = is13 ? g.B0 + (size_t)z * 65536 : g.B0 + 1179648 + (size_t)(z - 18) * 32768;
  const u16* Wf = g.Wb + (size_t)z * 524288;
  u16* Cb; int flag;
  if (is13) {
    const int slot = (z >= 16) ? 8 : (z & 7);
    Cb = g.C13 + (size_t)slot * 1048576;
    flag = (z >= 8 && z < 16) || z == 17 ? 2 : 1;
  } else {
    Cb = g.C2e + (size_t)(z - 18) * 524288;
    flag = 0;
  }

  const int wr = wave >> 1, wc = wave & 1;
  const int m0 = bx * 128, n0 = by * 128;
  u16* As = smem;
  u16* Bs = smem + 4096;
  u16* stage = smem + 8192;

  if (wave == 0) {
    float m = fmaxf(g.amaxP[z * 128 + lane], g.amaxP[z * 128 + 64 + lane]);
#pragma unroll
    for (int off = 32; off > 0; off >>= 1) m = fmaxf(m, __shfl_xor(m, off));
    if (lane == 0) s_sw = fmaxf(m / 127.f, 1e-8f);
  }

  const int ldrow = tid >> 2;
  const int swzcol = (((tid & 3) ^ ((tid >> 3) & 3)) << 3);
  const u16* ga = Ap + (size_t)(m0 + ldrow) * K + swzcol;
  const u16* gb = Bp + (size_t)(n0 + ldrow) * K + swzcol;
  const size_t rowstep = (size_t)64 * K;

  f4v acc[4][4];
#pragma unroll
  for (int i = 0; i < 4; i++)
#pragma unroll
    for (int j = 0; j < 4; j++) acc[i][j] = (f4v){0.f, 0.f, 0.f, 0.f};

  const int rbase = lane & 15;
  const int q = lane >> 4;
  const int pg = (q ^ ((rbase >> 1) & 3)) << 3;
  const int arow = (wr << 6) + rbase;
  const int brow = (wc << 6) + rbase;

  for (int kt = 0; kt < K; kt += 32) {
    __builtin_amdgcn_global_load_lds((const __attribute__((address_space(1))) void*)(ga),
        (__attribute__((address_space(3))) void*)&As[tid * 8], 16, 0, 0);
    __builtin_amdgcn_global_load_lds((const __attribute__((address_space(1))) void*)(ga + rowstep),
        (__attribute__((address_space(3))) void*)&As[(256 + tid) * 8], 16, 0, 0);
    __builtin_amdgcn_global_load_lds((const __attribute__((address_space(1))) void*)(gb),
        (__attribute__((address_space(3))) void*)&Bs[tid * 8], 16, 0, 0);
    __builtin_amdgcn_global_load_lds((const __attribute__((address_space(1))) void*)(gb + rowstep),
        (__attribute__((address_space(3))) void*)&Bs[(256 + tid) * 8], 16, 0, 0);
    ga += 32; gb += 32;
    __syncthreads();
    bfrag af[4], bf[4];
#pragma unroll
    for (int mi = 0; mi < 4; mi++)
      af[mi] = *(const bfrag*)&As[(arow + mi * 16) * 32 + pg];
#pragma unroll
    for (int ni = 0; ni < 4; ni++)
      bf[ni] = *(const bfrag*)&Bs[(brow + ni * 16) * 32 + pg];
#pragma unroll
    for (int mi = 0; mi < 4; mi++)
#pragma unroll
      for (int ni = 0; ni < 4; ni++)
        acc[mi][ni] = __builtin_amdgcn_mfma_f32_16x16x32_bf16(af[mi], bf[ni], acc[mi][ni], 0, 0, 0);
    __syncthreads();
  }

  const int lrow0 = (wr << 6) + ((lane >> 4) << 2);
  const int lcol0 = (wc << 6) + (lane & 15);
#pragma unroll
  for (int mi = 0; mi < 4; mi++)
#pragma unroll
    for (int ni = 0; ni < 4; ni++) {
      const int n = lcol0 + ni * 16;
#pragma unroll
      for (int r = 0; r < 4; r++)
        stage[(lrow0 + mi * 16 + r) * 136 + n] = f2bf(acc[mi][ni][r]);
    }
  __syncthreads();
  const float sw = s_sw;

  const int dm0 = flag ? (((m0 >> 7) << 8) + (flag == 2 ? 128 : 0)) : m0;
#pragma unroll
  for (int j = 0; j < 8; j++) {
    const int s = j * 256 + tid;
    const int lr = s >> 4;
    const int n8 = (s & 15) << 3;
    const u16x8 wv = *(const u16x8*)&Wf[(size_t)(m0 + lr) * N + n0 + n8];
    const bfrag sv = *(const bfrag*)&stage[lr * 136 + n8];
    u16x8 o;
#pragma unroll
    for (int k = 0; k < 8; k++)
      o[k] = f2bf(fq1(bf2f(wv[k]), sw) + bf2f((u16)sv[k]));
    *(u16x8*)&Cb[(size_t)(dm0 + lr) * N + n0 + n8] = o;
  }
}

// ---------------- prep: amax+convW (blocks 0..3455) + conversions (3456..7551) ----------------
struct PrepArgs {
  const float* W[27]; u16* Wraw; float* amaxP;
  const float* xf; u16* xfb;
  const float* p1w; u16* p1wb;
  const float* Asrc[27]; u16* Adst;
  const float* Bsrc[27]; u16* Bdst;
};
__global__ __launch_bounds__(256) void prep_kernel(PrepArgs a) {
  const int bid = blockIdx.x;
  const int tid = threadIdx.x;
  if (bid < 3456) {
    const int t = bid >> 7;
    const int bx = bid & 127;
    const float4* src = (const float4*)a.W[t];
    ushort4* dst = (ushort4*)(a.Wraw + (size_t)t * 524288);
    const int i0 = bx * 256 + tid;
    float4 v0 = src[i0];
    float4 v1 = src[i0 + 32768];
    float4 v2 = src[i0 + 65536];
    float4 v3 = src[i0 + 98304];
    ushort4 o0, o1, o2, o3;
    o0.x = f2bf(v0.x); o0.y = f2bf(v0.y); o0.z = f2bf(v0.z); o0.w = f2bf(v0.w);
    o1.x = f2bf(v1.x); o1.y = f2bf(v1.y); o1.z = f2bf(v1.z); o1.w = f2bf(v1.w);
    o2.x = f2bf(v2.x); o2.y = f2bf(v2.y); o2.z = f2bf(v2.z); o2.w = f2bf(v2.w);
    o3.x = f2bf(v3.x); o3.y = f2bf(v3.y); o3.z = f2bf(v3.z); o3.w = f2bf(v3.w);
    dst[i0] = o0; dst[i0 + 32768] = o1; dst[i0 + 65536] = o2; dst[i0 + 98304] = o3;
    float m01 = fmaxf(fmaxf(fabsf(v0.x), fabsf(v0.y)), fmaxf(fabsf(v0.z), fabsf(v0.w)));
    float m11 = fmaxf(fmaxf(fabsf(v1.x), fabsf(v1.y)), fmaxf(fabsf(v1.z), fabsf(v1.w)));
    float m21 = fmaxf(fmaxf(fabsf(v2.x), fabsf(v2.y)), fmaxf(fabsf(v2.z), fabsf(v2.w)));
    float m31 = fmaxf(fmaxf(fabsf(v3.x), fabsf(v3.y)), fmaxf(fabsf(v3.z), fabsf(v3.w)));
    float lmax = fmaxf(fmaxf(m01, m11), fmaxf(m21, m31));
#pragma unroll
    for (int off = 32; off > 0; off >>= 1) lmax = fmaxf(lmax, __shfl_xor(lmax, off));
    __shared__ float wm[4];
    if ((tid & 63) == 0) wm[tid >> 6] = lmax;
    __syncthreads();
    if (tid == 0)
      a.amaxP[t * 128 + bx] = fmaxf(fmaxf(wm[0], wm[1]), fmaxf(wm[2], wm[3]));
    return;
  }
  const int cid = bid - 3456;
  const int slice = cid >> 10;
  const int g0 = (cid & 1023) * 256 + tid;
  const int stride = 262144;
  if (slice == 0) {
    for (int i = g0; i < 1048576; i += stride) {
      float4 v = ((const float4*)a.xf)[i];
      ushort4 o; o.x = f2bf(v.x); o.y = f2bf(v.y); o.z = f2bf(v.z); o.w = f2bf(v.w);
      ((ushort4*)a.xfb)[i] = o;
    }
  } else if (slice == 1) {
    for (int i = g0; i < 65536; i += stride) {
      float4 v = ((const float4*)a.p1w)[i];
      ushort4 o; o.x = f2bf(v.x); o.y = f2bf(v.y); o.z = f2bf(v.z); o.w = f2bf(v.w);
      ((ushort4*)a.p1wb)[i] = o;
    }
  } else if (slice == 2) {
    for (int i = g0; i < 1179648; i += stride) {
      int t, off;
      if (i < 589824) { t = i >> 15; off = i & 32767; }
      else { int j = i - 589824; t = 18 + (j >> 16); off = j & 65535; }
      a.Adst[i] = f2bf(a.Asrc[t][off]);
    }
  } else {
    for (int i = g0; i < 1474560; i += stride) {
      int t, src;
      if (i < 1179648) { t = i >> 16; int off = i & 65535; src = (off & 63) * 1024 + (off >> 6); }
      else { int j = i - 1179648; t = 18 + (j >> 15); int off = j & 32767; src = (off & 63) * 512 + (off >> 6); }
      a.Bdst[i] = f2bf(a.Bsrc[t][src]);
    }
  }
}

// ---------------- router: logits (16 tokens/block) + topk fused ----------------
struct RouterArgs {
  const float* xf; const u16* ph;
  const float* sw; const float* sb;
  const float* p2w; const float* p2b;
  int* idx2; float2* wb;
  float* partials;   // [256][10]
  int* histArr;      // [256][8]
};
__global__ __launch_bounds__(256) void router_kernel(RouterArgs a) {
  __shared__ float sw[8][1024];
  __shared__ float p2[8][256];
  __shared__ float blog[16][8];
  __shared__ float plog[16][8];
  __shared__ int hist[8];
  const int tid = threadIdx.x;
  {
    const float4* s0 = (const float4*)a.sw;
    float4* d0 = (float4*)&sw[0][0];
    for (int i = tid; i < 2048; i += 256) d0[i] = s0[i];
    const float4* s1 = (const float4*)a.p2w;
    float4* d1 = (float4*)&p2[0][0];
    for (int i = tid; i < 512; i += 256) d1[i] = s1[i];
  }
  if (tid < 8) hist[tid] = 0;
  __syncthreads();
  const int tl = tid >> 4, s = tid & 15;
  const int token = blockIdx.x * 16 + tl;
  {
    float acc[8] = {0,0,0,0,0,0,0,0}, pacc[8] = {0,0,0,0,0,0,0,0};
    const float4* xrow = (const float4*)(a.xf + (size_t)token * 1024);
    for (int i = 0; i < 16; i++) {
      const int d4 = i * 16 + s;
      float4 xv = xrow[d4];
#pragma unroll
      for (int e = 0; e < 8; e++) {
        float4 wv = ((const float4*)&sw[e][0])[d4];
        acc[e] += xv.x * wv.x + xv.y * wv.y + xv.z * wv.z + xv.w * wv.w;
      }
    }
    const u16* phrow = a.ph + (size_t)token * 256;
    for (int i = 0; i < 16; i++) {
      const int h = i * 16 + s;
      float pv = bf2f(phrow[h]);
#pragma unroll
      for (int e = 0; e < 8; e++) pacc[e] += pv * p2[e][h];
    }
#pragma unroll
    for (int off = 8; off > 0; off >>= 1)
#pragma unroll
      for (int e = 0; e < 8; e++) {
        acc[e] += __shfl_xor(acc[e], off);
        pacc[e] += __shfl_xor(pacc[e], off);
      }
    if (s == 0) {
#pragma unroll
      for (int e = 0; e < 8; e++) {
        blog[tl][e] = acc[e] + a.sb[e];
        plog[tl][e] = pacc[e] + a.p2b[e];
      }
    }
  }
  __syncthreads();

  float vals[10];
#pragma unroll
  for (int v = 0; v < 10; v++) vals[v] = 0.f;
  if (tid < 16) {
    const int tok = blockIdx.x * 16 + tid;
    float b[8], p[8];
#pragma unroll
    for (int e = 0; e < 8; e++) { b[e] = blog[tid][e]; p[e] = plog[tid][e]; }
    float pm = p[0];
#pragma unroll
    for (int e = 1; e < 8; e++) pm = fmaxf(pm, p[e]);
    float pe[8], psum = 0.f;
#pragma unroll
    for (int e = 0; e < 8; e++) { pe[e] = expf(p[e] - pm); psum += pe[e]; }
    const float pinv = 1.f / psum;
    float sl[8];
#pragma unroll
    for (int e = 0; e < 8; e++) sl[e] = (b[e] + pe[e] * pinv) * 0.5f;
    float sm = sl[0];
#pragma unroll
    for (int e = 1; e < 8; e++) sm = fmaxf(sm, sl[e]);
    float sc[8], ssum = 0.f;
#pragma unroll
    for (int e = 0; e < 8; e++) { sc[e] = expf(sl[e] - sm); ssum += sc[e]; }
    const float sinv = 1.f / ssum;
    float ent = 0.f;
#pragma unroll
    for (int e = 0; e < 8; e++) { float v = sc[e] * sinv; sc[e] = v; ent -= v * logf(v + 1e-6f); }
    float bm = b[0];
#pragma unroll
    for (int e = 1; e < 8; e++) bm = fmaxf(bm, b[e]);
    float zs = 0.f;
#pragma unroll
    for (int e = 0; e < 8; e++) zs += expf(b[e] - bm);
    const float lse = logf(zs) + bm;
    float m1 = -1e30f, m2 = -1e30f; int i1 = 0, i2 = 0;
#pragma unroll
    for (int e = 0; e < 8; e++) {
      float v = sc[e];
      if (v > m1) { m2 = m1; i2 = i1; m1 = v; i1 = e; }
      else if (v > m2) { m2 = v; i2 = e; }
    }
    a.idx2[tok] = i1 | (i2 << 8);
    a.wb[tok] = make_float2(m1, m2);
    atomicAdd(&hist[i1], 1);
    atomicAdd(&hist[i2], 1);
    vals[0] = ent; vals[1] = lse * lse;
    vals[2 + i1] = m1; vals[2 + i2] = m2;
  }
  if (tid < 64) {
#pragma unroll
    for (int v = 0; v < 10; v++)
#pragma unroll
      for (int off = 32; off > 0; off >>= 1) vals[v] += __shfl_down(vals[v], off);
    if (tid == 0)
#pragma unroll
      for (int v = 0; v < 10; v++) a.partials[blockIdx.x * 10 + v] = vals[v];
  }
  __syncthreads();
  if (tid < 8) a.histArr[blockIdx.x * 8 + tid] = hist[tid];
}

// ---------------- compaction + setup + losses (9 blocks, cooperative reductions) ----------------
__global__ __launch_bounds__(256) void compact_setup(const int* idx2, const int* histArr,
                                                     int2* blkmap, int* nbrow, int* tokmap,
                                                     int* posb, const float* partials, float* tail) {
  const int e = blockIdx.x;
  const int tid = threadIdx.x;
  const int lane = tid & 63, wv = tid >> 6;
  __shared__ int scnt[8];
  __shared__ int wcnt[4][8];

  {
    int local[8];
#pragma unroll
    for (int i = 0; i < 8; i++) local[i] = histArr[tid * 8 + i];
#pragma unroll
    for (int i = 0; i < 8; i++) {
      int v = local[i];
#pragma unroll
      for (int off = 32; off > 0; off >>= 1) v += __shfl_down(v, off);
      if (lane == 0) wcnt[wv][i] = v;
    }
  }
  __syncthreads();
  if (tid < 8) scnt[tid] = wcnt[0][tid] + wcnt[1][tid] + wcnt[2][tid] + wcnt[3][tid];
  __syncthreads();

  if (e == 8) {
    __shared__ float wpart[4][10];
    float pv[10];
#pragma unroll
    for (int v = 0; v < 10; v++) pv[v] = partials[tid * 10 + v];
#pragma unroll
    for (int v = 0; v < 10; v++) {
      float t = pv[v];
#pragma unroll
      for (int off = 32; off > 0; off >>= 1) t += __shfl_down(t, off);
      if (lane == 0) wpart[wv][v] = t;
    }
    __syncthreads();
    if (tid == 0) {
      float pt[10];
#pragma unroll
      for (int v = 0; v < 10; v++)
        pt[v] = wpart[0][v] + wpart[1][v] + wpart[2][v] + wpart[3][v];
      const float ent = pt[0], z = pt[1];
      float us[8];
      for (int ex = 0; ex < 8; ex++) us[ex] = pt[2 + ex];
      float tot = 0.f;
      for (int ex = 0; ex < 8; ex++) tot += us[ex];
      const float meanu = tot / 8.f;
      float uf[8], mu = 0.f;
      for (int ex = 0; ex < 8; ex++) { uf[ex] = us[ex] / (meanu + 1e-6f); mu += uf[ex]; }
      mu /= 8.f;
      float var = 0.f;
      for (int ex = 0; ex < 8; ex++) { float d = uf[ex] - mu; var += d * d; }
      var /= 7.f;
      const float bl = 0.3f * var - 0.1f * (ent / 4096.f) + 1e-4f * (z / 4096.f);
      for (int ex = 0; ex < 8; ex++) tail[ex] = us[ex];
      tail[8] = bl; tail[9] = 0.f; tail[10] = 0.f;
      int o = 0, nb = 16;
      for (int i = 0; i < 16; i++) blkmap[i] = make_int2(8, i * 256);
      for (int ex = 0; ex < 8; ex++) {
        const int nbe = (scnt[ex] + 255) >> 8;
        for (int i = 0; i < nbe; i++) blkmap[nb++] = make_int2(ex, 4096 + o + i * 256);
        o += nbe << 8;
      }
      nbrow[0] = nb;
    }
    for (int t = tid; t < 4096; t += 256) tokmap[t] = t;
    return;
  }

  __shared__ int wtot[4];
  __shared__ int carry;
  if (tid == 0) carry = 0;
  __syncthreads();
  int off = 0;
  for (int i = 0; i < e; i++) off += ((scnt[i] + 255) >> 8) << 8;
  const int base = 4096 + off;
  for (int c = 0; c < 16; c++) {
    const int t = c * 256 + tid;
    const int ii = idx2[t];
    const int i1 = ii & 255, i2 = ii >> 8;
    const int flag = (i1 == e || i2 == e) ? 1 : 0;
    const unsigned long long m = __ballot(flag);
    const int pre = __popcll(m & ((1ull << lane) - 1ull));
    if (lane == 63) wtot[wv] = pre + flag;
    __syncthreads();
    int wbase = 0;
    for (int i = 0; i < wv; i++) wbase += wtot[i];
    if (flag) {
      const int row = base + carry + wbase + pre;
      tokmap[row] = t;
      posb[t * 2 + (i2 == e ? 1 : 0)] = row;
    }
    __syncthreads();
    if (tid == 0) carry += wtot[0] + wtot[1] + wtot[2] + wtot[3];
    __syncthreads();
  }
  const int ce = scnt[e];
  const int pend = ((ce + 255) >> 8) << 8;
  for (int r = ce + tid; r < pend; r += 256) tokmap[base + r] = 0;
}

// ---------------- combine: out[t] = y2c[t] + w1*y2c[p1] + w2*y2c[p2] ----------------
__global__ __launch_bounds__(256) void combine_g(const u16* y2c, const int* posb,
                                                 const float2* wb, float* out) {
  const int t = blockIdx.x;
  const int c = threadIdx.x;
  const float2 w = wb[t];
  const int p1 = posb[t * 2], p2 = posb[t * 2 + 1];
  ushort4 s = ((const ushort4*)(y2c + (size_t)t * 1024))[c];
  ushort4 a = ((const ushort4*)(y2c + (size_t)p1 * 1024))[c];
  ushort4 b = ((const ushort4*)(y2c + (size_t)p2 * 1024))[c];
  float4 o;
  o.x = bf2f(s.x) + w.x * bf2f(a.x) + w.y * bf2f(b.x);
  o.y = bf2f(s.y) + w.x * bf2f(a.y) + w.y * bf2f(b.y);
  o.z = bf2f(s.z) + w.x * bf2f(a.z) + w.y * bf2f(b.z);
  o.w = bf2f(s.w) + w.x * bf2f(a.w) + w.y * bf2f(b.w);
  ((float4*)(out + (size_t)t * 1024))[c] = o;
}

// ---------------- host ----------------
extern "C" void kernel_launch(void* const* d_in, const int* in_sizes, int n_in,
                              void* d_out, int out_size, void* d_ws, size_t ws_size,
                              hipStream_t stream) {
  const float* x = (const float*)d_in[0];
  const float* scorer_w = (const float*)d_in[1];
  const float* scorer_b = (const float*)d_in[2];
  const float* p1_w = (const float*)d_in[3];
  const float* p1_b = (const float*)d_in[4];
  const float* p2_w = (const float*)d_in[5];
  const float* p2_b = (const float*)d_in[6];
  const float* ew1_w = (const float*)d_in[7];
  const float* ew1_a = (const float*)d_in[8];
  const float* ew1_b = (const float*)d_in[9];
  const float* ew2_w = (const float*)d_in[10];
  const float* ew2_a = (const float*)d_in[11];
  const float* ew2_b = (const float*)d_in[12];
  const float* ew3_w = (const float*)d_in[13];
  const float* ew3_a = (const float*)d_in[14];
  const float* ew3_b = (const float*)d_in[15];
  const float* s1_w = (const float*)d_in[16];
  const float* s1_a = (const float*)d_in[17];
  const float* s1_b = (const float*)d_in[18];
  const float* s2_w = (const float*)d_in[19];
  const float* s2_a = (const float*)d_in[20];
  const float* s2_b = (const float*)d_in[21];
  const float* s3_w = (const float*)d_in[22];
  const float* s3_a = (const float*)d_in[23];
  const float* s3_b = (const float*)d_in[24];
  float* outf = (float*)d_out;

  char* w = (char*)d_ws;
  auto alloc = [&](size_t bytes) { char* p = w; w += (bytes + 255) & ~(size_t)255; return p; };
  u16* xfb  = (u16*)alloc((size_t)TTOK * DDIM * 2);
  u16* ph   = (u16*)alloc((size_t)TTOK * HDIM * 2);
  u16* p1wb = (u16*)alloc((size_t)HDIM * DDIM * 2);
  u16* Adst = (u16*)alloc((size_t)1179648 * 2);
  u16* Bdst = (u16*)alloc((size_t)1474560 * 2);
  u16* Wraw = (u16*)alloc((size_t)27 * 524288 * 2);
  u16* W13  = (u16*)alloc((size_t)9 * 1024 * 1024 * 2);
  u16* W2e  = (u16*)alloc((size_t)9 * 1024 * 512 * 2);
  u16* h2c  = (u16*)alloc((size_t)CROWS * FDIM * 2);
  u16* y2c  = (u16*)alloc((size_t)CROWS * DDIM * 2);
  float* partials = (float*)alloc(256 * 10 * 4);
  float* amaxP = (float*)alloc(27 * 128 * 4);
  int* histArr = (int*)alloc(256 * 8 * 4);
  int2* blkmap = (int2*)alloc(64 * 8);
  int* nbrow  = (int*)alloc(4);
  int* tokmap = (int*)alloc(CROWS * 4);
  int* posb   = (int*)alloc(TTOK * 2 * 4);
  int* idx2   = (int*)alloc(TTOK * 4);
  float2* wb  = (float2*)alloc(TTOK * 8);

  // 1. prep: W amax partials + W->bf16 + all conversions
  {
    PrepArgs a{};
    for (int e = 0; e < 8; e++) {
      a.W[e] = ew1_w + (size_t)e * 524288;
      a.W[8 + e] = ew3_w + (size_t)e * 524288;
      a.W[18 + e] = ew2_w + (size_t)e * 524288;
      a.Asrc[e] = ew1_a + (size_t)e * 32768;
      a.Asrc[8 + e] = ew3_a + (size_t)e * 32768;
      a.Asrc[18 + e] = ew2_a + (size_t)e * 65536;
      a.Bsrc[e] = ew1_b + (size_t)e * 65536;
      a.Bsrc[8 + e] = ew3_b + (size_t)e * 65536;
      a.Bsrc[18 + e] = ew2_b + (size_t)e * 32768;
    }
    a.W[16] = s1_w; a.W[17] = s3_w; a.W[26] = s2_w;
    a.Asrc[16] = s1_a; a.Asrc[17] = s3_a; a.Asrc[26] = s2_a;
    a.Bsrc[16] = s1_b; a.Bsrc[17] = s3_b; a.Bsrc[26] = s2_b;
    a.Wraw = Wraw; a.amaxP = amaxP;
    a.xf = x; a.xfb = xfb; a.p1w = p1_w; a.p1wb = p1wb;
    a.Adst = Adst; a.Bdst = Bdst;
    hipLaunchKernelGGL(prep_kernel, dim3(7552), dim3(256), 0, stream, a);
  }
  // 2. mid: router hidden gemm64 + merged LoRA fold
  {
    MidArgs g{};
    g.A64 = xfb; g.B64 = p1wb; g.C64 = ph; g.bias64 = p1_b;
    g.A0 = Adst; g.B0 = Bdst; g.Wb = Wraw; g.C13 = W13; g.C2e = W2e; g.amaxP = amaxP;
    hipLaunchKernelGGL(mid_kernel, dim3(1984), dim3(256), 0, stream, g);
  }
  // 3. router: logits + topk fused
  {
    RouterArgs r{};
    r.xf = x; r.ph = ph; r.sw = scorer_w; r.sb = scorer_b;
    r.p2w = p2_w; r.p2b = p2_b;
    r.idx2 = idx2; r.wb = wb; r.partials = partials; r.histArr = histArr;
    hipLaunchKernelGGL(router_kernel, dim3(256), dim3(256), 0, stream, r);
  }
  // 4. compaction + setup + losses (9 blocks)
  hipLaunchKernelGGL(compact_setup, dim3(9), dim3(256), 0, stream,
                     idx2, histArr, blkmap, nbrow, tokmap, posb, partials,
                     outf + (size_t)TTOK * DDIM);
  // 5. y13 + fused h2 over gathered rows (16-wave blocks)
  {
    GemmGArgs g{xfb, W13, h2c, tokmap, blkmap, nbrow};
    hipLaunchKernelGGL(gemm256g<1>, dim3(224), dim3(1024), 0, stream, g);
  }
  // 6. y2 over concat rows
  {
    GemmGArgs g{h2c, W2e, y2c, tokmap, blkmap, nbrow};
    hipLaunchKernelGGL(gemm256g<0>, dim3(224), dim3(1024), 0, stream, g);
  }
  // 7. deterministic combine
  hipLaunchKernelGGL(combine_g, dim3(4096), dim3(256), 0, stream, y2c, posb, wb, outf);
}